// Round 5
// baseline (637.094 us; speedup 1.0000x reference)
//
#include <hip/hip_runtime.h>
#include <math.h>

// Shapes
#define B_   128
#define D_   1024
#define H_   256
#define M_   100
#define K_   5
#define MD   102400   // M_*D_
#define EPS_ 1e-5f

// d_out layout (f32): probs[128*100*1024], scores[12800], syn[12800], logits[128*100*1024]
#define OFF_SCORES 13107200
#define OFF_SYN    13120000
#define OFF_LOGITS 13132800

// ---------------- reduction helpers ----------------
__device__ __forceinline__ float block_sum(float v, float* red, int t) {
  #pragma unroll
  for (int off = 1; off < 64; off <<= 1) v += __shfl_xor(v, off);
  if ((t & 63) == 0) red[t >> 6] = v;
  __syncthreads();
  float s = red[0] + red[1] + red[2] + red[3];
  __syncthreads();
  return s;
}

__device__ __forceinline__ float block_max(float v, float* red, int t) {
  #pragma unroll
  for (int off = 1; off < 64; off <<= 1) v = fmaxf(v, __shfl_xor(v, off));
  if ((t & 63) == 0) red[t >> 6] = v;
  __syncthreads();
  float s = fmaxf(fmaxf(red[0], red[1]), fmaxf(red[2], red[3]));
  __syncthreads();
  return s;
}

__device__ __forceinline__ void block_sum2(float& a, float& b, float* red, int t) {
  #pragma unroll
  for (int off = 1; off < 64; off <<= 1) { a += __shfl_xor(a, off); b += __shfl_xor(b, off); }
  if ((t & 63) == 0) { red[(t >> 6) * 2] = a; red[(t >> 6) * 2 + 1] = b; }
  __syncthreads();
  a = red[0] + red[2] + red[4] + red[6];
  b = red[1] + red[3] + red[5] + red[7];
  __syncthreads();
}

// ---------------- K1: generator layers 1+2 (per batch row) ----------------
__global__ __launch_bounds__(256) void gen_mlp_kernel(
    const float* __restrict__ x,
    const float* __restrict__ gW1, const float* __restrict__ gb1,
    const float* __restrict__ ln1s, const float* __restrict__ ln1b,
    const float* __restrict__ gW2, const float* __restrict__ gb2,
    const float* __restrict__ ln2s, const float* __restrict__ ln2b,
    float* __restrict__ h2out)
{
  __shared__ float xs[1024];
  __shared__ float h1s[512];
  __shared__ float red[8];
  int b = blockIdx.x, t = threadIdx.x;
  const float* xr = x + b * 1024;
  #pragma unroll
  for (int i = 0; i < 4; ++i) xs[t + i * 256] = xr[t + i * 256];
  __syncthreads();

  // layer1: thread computes outputs o=2t, 2t+1 (512 outputs)
  float a0 = 0.f, a1 = 0.f;
  for (int d = 0; d < 1024; ++d) {
    float xv = xs[d];
    float2 w = *(const float2*)&gW1[d * 512 + 2 * t];
    a0 = fmaf(xv, w.x, a0);
    a1 = fmaf(xv, w.y, a1);
  }
  a0 += gb1[2 * t]; a1 += gb1[2 * t + 1];
  float s = a0 + a1, sq = a0 * a0 + a1 * a1;
  block_sum2(s, sq, red, t);
  float mu = s * (1.f / 512.f);
  float var = sq * (1.f / 512.f) - mu * mu;
  float inv = rsqrtf(var + EPS_);
  h1s[2 * t]     = fmaxf((a0 - mu) * inv * ln1s[2 * t]     + ln1b[2 * t],     0.f);
  h1s[2 * t + 1] = fmaxf((a1 - mu) * inv * ln1s[2 * t + 1] + ln1b[2 * t + 1], 0.f);
  __syncthreads();

  // layer2: thread computes output o=t (256 outputs)
  float acc = 0.f;
  for (int h = 0; h < 512; ++h) acc = fmaf(h1s[h], gW2[h * 256 + t], acc);
  acc += gb2[t];
  float s2 = acc, sq2 = acc * acc;
  block_sum2(s2, sq2, red, t);
  float mu2 = s2 * (1.f / 256.f);
  float var2 = sq2 * (1.f / 256.f) - mu2 * mu2;
  float inv2 = rsqrtf(var2 + EPS_);
  h2out[b * 256 + t] = fmaxf((acc - mu2) * inv2 * ln2s[t] + ln2b[t], 0.f);
}

// ---------------- K2: logits = h2 @ gW3 + gb3  (128 x 102400, K=256) ----------------
// Round-5: counted-vmcnt 2-deep DMA pipeline (T4). BK=16, W triple-buffered
// (3 x 8 KB) via global_load_lds; per-phase wait is vmcnt(2) -- the NEXT
// tile's 2 DMA issues stay in flight across the barrier; a full drain happens
// only at the last tile. h2 staged reg->LDS; fences pin vmcnt queue order
// [DMA(kt+1), h2(kt+1), DMA(kt+2)] so vmcnt(2) drains exactly what tile kt+1
// needs. LDS 33 KB -> 4 blocks/CU (16 waves). kk order 0..255 sequential ->
// bit-identical logits.
__global__ __launch_bounds__(256, 4) void gemm3_kernel(
    const float* __restrict__ h2, const float* __restrict__ gW3,
    const float* __restrict__ gb3, float* __restrict__ logits)
{
  __shared__ float h2t[16 * 132];       // A tile [kk][row], 8.45 KB
  __shared__ float Wlds[3 * 16 * 128];  // B tiles, triple buffer, 24 KB
  int t = threadIdx.x;
  int lane = t & 63;
  int wv = t >> 6;                      // wave id 0..3
  int rg8 = (t >> 4) * 8;               // row-group base 0..120
  int cg4 = (t & 15) * 4;               // col-frag base 0..60
  long col0 = (long)blockIdx.x * 128;

  int bb = t >> 1;                      // h2 staging: row 0..127
  int ks = (t & 1) * 8;                 // h2 staging: kk offset 0 or 8

  int krl = lane >> 5;                  // DMA: sub kk-row 0/1 within 1KB chunk
  int cid = (lane & 31) * 4;            // DMA: col float offset

  float acc[8][8];
  #pragma unroll
  for (int i = 0; i < 8; ++i)
    #pragma unroll
    for (int j = 0; j < 8; ++j) acc[i][j] = 0.f;

  // W DMA for tile kt_ into buffer slot s_ (2 chunks of 1KB per wave)
#define ISSUE_W(kt_, s_)                                                           \
  {                                                                                \
    int c0_ = wv * 2;                                                              \
    const float* g0_ = gW3 + ((long)(kt_) * 16 + 2 * c0_ + krl) * MD + col0 + cid; \
    float* l0_ = &Wlds[(s_) * 2048 + c0_ * 256];                                   \
    __builtin_amdgcn_global_load_lds(                                              \
        (const __attribute__((address_space(1))) void*)g0_,                        \
        (__attribute__((address_space(3))) void*)l0_, 16, 0, 0);                   \
    int c1_ = wv * 2 + 1;                                                          \
    const float* g1_ = gW3 + ((long)(kt_) * 16 + 2 * c1_ + krl) * MD + col0 + cid; \
    float* l1_ = &Wlds[(s_) * 2048 + c1_ * 256];                                   \
    __builtin_amdgcn_global_load_lds(                                              \
        (const __attribute__((address_space(1))) void*)g1_,                        \
        (__attribute__((address_space(3))) void*)l1_, 16, 0, 0);                   \
  }

  // ---- prologue: queue order = DMA(0), h2(0), DMA(1) ----
  ISSUE_W(0, 0);
  asm volatile("" ::: "memory");
  const float* hp0 = &h2[bb * 256 + ks];
  float4 ha = *(const float4*)(hp0);
  float4 hb = *(const float4*)(hp0 + 4);
  asm volatile("" ::: "memory");
  ISSUE_W(1, 1);

  #pragma unroll 1
  for (int kt = 0; kt < 16; ++kt) {
    // drain DMA(kt) + h2(kt); keep DMA(kt+1) (2 newest) in flight
    if (kt == 15) { asm volatile("s_waitcnt vmcnt(0)" ::: "memory"); }
    else         { asm volatile("s_waitcnt vmcnt(2)" ::: "memory"); }
    __builtin_amdgcn_s_barrier();   // prev compute done + this tile's W in LDS

    // stage h2 tile (transposed) from regs
    h2t[(ks + 0) * 132 + bb] = ha.x;
    h2t[(ks + 1) * 132 + bb] = ha.y;
    h2t[(ks + 2) * 132 + bb] = ha.z;
    h2t[(ks + 3) * 132 + bb] = ha.w;
    h2t[(ks + 4) * 132 + bb] = hb.x;
    h2t[(ks + 5) * 132 + bb] = hb.y;
    h2t[(ks + 6) * 132 + bb] = hb.z;
    h2t[(ks + 7) * 132 + bb] = hb.w;

    asm volatile("" ::: "memory");
    if (kt < 15) {                      // h2(kt+1) BEFORE DMA(kt+2): queue order
      const float* hq = &h2[bb * 256 + (kt + 1) * 16 + ks];
      ha = *(const float4*)(hq);
      hb = *(const float4*)(hq + 4);
    }
    asm volatile("" ::: "memory");
    if (kt < 14) ISSUE_W(kt + 2, (kt + 2) % 3);

    asm volatile("s_waitcnt lgkmcnt(0)" ::: "memory");
    __builtin_amdgcn_s_barrier();       // all waves' h2t writes visible

    // compute this tile
    const float* Wb = &Wlds[(kt % 3) * 2048];
    #pragma unroll
    for (int kk = 0; kk < 16; ++kk) {
      float4 a0 = *(const float4*)&h2t[kk * 132 + rg8];
      float4 a1 = *(const float4*)&h2t[kk * 132 + rg8 + 4];
      float4 b0 = *(const float4*)&Wb[kk * 128 + cg4];
      float4 b1 = *(const float4*)&Wb[kk * 128 + 64 + cg4];
      float a[8] = {a0.x, a0.y, a0.z, a0.w, a1.x, a1.y, a1.z, a1.w};
      float bvv[8] = {b0.x, b0.y, b0.z, b0.w, b1.x, b1.y, b1.z, b1.w};
      #pragma unroll
      for (int i = 0; i < 8; ++i)
        #pragma unroll
        for (int j = 0; j < 8; ++j)
          acc[i][j] = fmaf(a[i], bvv[j], acc[i][j]);
    }
  }
#undef ISSUE_W

  // epilogue: bias + store (cols cg4..+3 and 64+cg4..+3)
  float4 bias0 = *(const float4*)&gb3[col0 + cg4];
  float4 bias1 = *(const float4*)&gb3[col0 + 64 + cg4];
  #pragma unroll
  for (int i = 0; i < 8; ++i) {
    long row = rg8 + i;
    float4 o0, o1;
    o0.x = acc[i][0] + bias0.x; o0.y = acc[i][1] + bias0.y;
    o0.z = acc[i][2] + bias0.z; o0.w = acc[i][3] + bias0.w;
    o1.x = acc[i][4] + bias1.x; o1.y = acc[i][5] + bias1.y;
    o1.z = acc[i][6] + bias1.z; o1.w = acc[i][7] + bias1.w;
    *(float4*)&logits[row * MD + col0 + cg4] = o0;
    *(float4*)&logits[row * MD + col0 + 64 + cg4] = o1;
  }
}

// ---------------- K3: softmax + top-5 + gathers + synergy + t1 (per (b,m) row) ----------------
// Round-5: per-wave top-5 (barrier-free shuffle rounds) -> single merge of
// 4x5 candidates (exact same (val desc, idx asc) order) -> all 10 gather-row
// loads issued concurrently (1 HBM latency instead of 5 serialized).
// fmaf accumulation order per accumulator unchanged -> bit-identical t1/u1.
__global__ __launch_bounds__(256) void tail_kernel(
    const float* __restrict__ x, const float* __restrict__ gumbel,
    const float* __restrict__ sW1, const float* __restrict__ sb1,
    const float* __restrict__ yW1, const float* __restrict__ yb1,
    const float* __restrict__ yW2, const float* __restrict__ yb2,
    const float* __restrict__ logits, float* __restrict__ probs,
    float* __restrict__ syn, float* __restrict__ t1ws)
{
  __shared__ float red[8];
  __shared__ float candV[20];
  __shared__ int   candI[20];
  __shared__ int   wsel[5];
  int row = blockIdx.x;       // row = b*100 + m
  int t = threadIdx.x;
  int b = row / 100;
  const float* lg = logits + row * 1024;
  const float* gm = gumbel + row * 1024;

  // z = (logit + gumbel) / tau, tau = 0.5
  float z[4];
  #pragma unroll
  for (int i = 0; i < 4; ++i) z[i] = (lg[t + i * 256] + gm[t + i * 256]) * 2.0f;
  float mx = fmaxf(fmaxf(z[0], z[1]), fmaxf(z[2], z[3]));
  mx = block_max(mx, red, t);
  float p[4]; float ls = 0.f;
  #pragma unroll
  for (int i = 0; i < 4; ++i) { p[i] = expf(z[i] - mx); ls += p[i]; }
  float denom = block_sum(ls, red, t);
  float inv = 1.f / denom;
  float v[4];
  #pragma unroll
  for (int i = 0; i < 4; ++i) {
    v[i] = p[i] * inv;
    probs[row * 1024 + t + i * 256] = v[i];
  }

  // ---- stage 1: per-wave top-5 (no barriers; wave-synchronous) ----
  int wid = t >> 6;
  #pragma unroll
  for (int jsel = 0; jsel < 5; ++jsel) {
    float bv = v[0]; int bi = t;          // idx = i*256 + t
    #pragma unroll
    for (int i = 1; i < 4; ++i) {
      int idx = i * 256 + t;
      if (v[i] > bv || (v[i] == bv && idx < bi)) { bv = v[i]; bi = idx; }
    }
    #pragma unroll
    for (int off = 1; off < 64; off <<= 1) {
      float ov = __shfl_xor(bv, off);
      int oi = __shfl_xor(bi, off);
      if (ov > bv || (ov == bv && oi < bi)) { bv = ov; bi = oi; }
    }
    if ((t & 63) == 0) { candV[wid * 5 + jsel] = bv; candI[wid * 5 + jsel] = bi; }
    #pragma unroll
    for (int i = 0; i < 4; ++i)
      if (bi == i * 256 + t) v[i] = -1.f;   // static-indexed mask of wave winner
  }
  __syncthreads();

  // ---- stage 2: wave 0 merges 20 candidates into global top-5 ----
  // Removal via strictly-decreasing (val desc, idx asc) threshold: no
  // runtime-indexed arrays, exact same winners as serial global selection.
  if (t < 64) {
    float cV[20]; int cI[20];
    #pragma unroll
    for (int i = 0; i < 20; ++i) { cV[i] = candV[i]; cI[i] = candI[i]; }
    float pv = 2.0f; int pi = -1;         // sentinel above any prob
    int w0 = 0, w1 = 0, w2 = 0, w3 = 0, w4 = 0;
    #pragma unroll
    for (int jsel = 0; jsel < 5; ++jsel) {
      float bv = -1.0f; int bi = 0x7FFFFFFF;
      #pragma unroll
      for (int i = 0; i < 20; ++i) {
        bool ltp = (cV[i] < pv) || (cV[i] == pv && cI[i] > pi);
        bool gtc = (cV[i] > bv) || (cV[i] == bv && cI[i] < bi);
        if (ltp && gtc) { bv = cV[i]; bi = cI[i]; }
      }
      if      (jsel == 0) w0 = bi;
      else if (jsel == 1) w1 = bi;
      else if (jsel == 2) w2 = bi;
      else if (jsel == 3) w3 = bi;
      else                w4 = bi;
      pv = bv; pi = bi;
    }
    if (t == 0) { wsel[0] = w0; wsel[1] = w1; wsel[2] = w2; wsel[3] = w3; wsel[4] = w4; }
  }
  __syncthreads();

  // ---- stage 3: batched gathers (all loads independent -> one latency) ----
  int ws0 = wsel[0], ws1 = wsel[1], ws2 = wsel[2], ws3 = wsel[3], ws4 = wsel[4];
  const float* xb = x + b * 1024;
  float x0 = xb[ws0], x1 = xb[ws1], x2 = xb[ws2], x3 = xb[ws3], x4 = xb[ws4];

  float t1acc = sb1[t];
  t1acc = fmaf(x0, sW1[(0 * 1024 + ws0) * 256 + t], t1acc);
  t1acc = fmaf(x1, sW1[(1 * 1024 + ws1) * 256 + t], t1acc);
  t1acc = fmaf(x2, sW1[(2 * 1024 + ws2) * 256 + t], t1acc);
  t1acc = fmaf(x3, sW1[(3 * 1024 + ws3) * 256 + t], t1acc);
  t1acc = fmaf(x4, sW1[(4 * 1024 + ws4) * 256 + t], t1acc);

  float u1acc = yb1[t];
  u1acc = fmaf(x0, yW1[(0 * 1024 + ws0) * 256 + t], u1acc);
  u1acc = fmaf(x1, yW1[(1 * 1024 + ws1) * 256 + t], u1acc);
  u1acc = fmaf(x2, yW1[(2 * 1024 + ws2) * 256 + t], u1acc);
  u1acc = fmaf(x3, yW1[(3 * 1024 + ws3) * 256 + t], u1acc);
  u1acc = fmaf(x4, yW1[(4 * 1024 + ws4) * 256 + t], u1acc);

  float t1v = fmaxf(t1acc, 0.f);
  float u1v = fmaxf(u1acc, 0.f);
  t1ws[row * 256 + t] = t1v;

  // synergy = tanh(u1 . yW2 + yb2)
  float part = u1v * yW2[t];
  float dsum = block_sum(part, red, t);
  if (t == 0) syn[row] = tanhf(dsum + yb2[0]);
}

// ---------------- K4: scores = sigmoid(relu(t1 @ sW2 + sb2) @ sW3 + sb3) ----------------
// Block = 64 rows x 128 cols, K=256; thread = 8 rows x 4 cols.
__global__ __launch_bounds__(256) void scorer2_kernel(
    const float* __restrict__ t1, const float* __restrict__ sW2,
    const float* __restrict__ sb2, const float* __restrict__ sW3,
    const float* __restrict__ sb3, float* __restrict__ scores)
{
  __shared__ float t1t[64 * 68];   // [kk][row], stride 68 (16B-aligned)
  __shared__ float red[64 * 32];
  int t = threadIdx.x;
  int row0 = blockIdx.x * 64;
  int c4 = (t & 31) * 4;
  int r8 = (t >> 5) * 8;
  float acc[8][4];
  #pragma unroll
  for (int i = 0; i < 8; ++i)
    #pragma unroll
    for (int j = 0; j < 4; ++j) acc[i][j] = 0.f;

  for (int c = 0; c < 4; ++c) {
    #pragma unroll
    for (int p = 0; p < 16; ++p) {
      int rr = p * 4 + (t >> 6);
      int kk = t & 63;
      t1t[kk * 68 + rr] = t1[(row0 + rr) * 256 + c * 64 + kk];
    }
    __syncthreads();
    #pragma unroll 4
    for (int kk = 0; kk < 64; ++kk) {
      float4 bf = *(const float4*)&sW2[(c * 64 + kk) * 128 + c4];
      float4 a0 = *(const float4*)&t1t[kk * 68 + r8];
      float4 a1 = *(const float4*)&t1t[kk * 68 + r8 + 4];
      float a[8] = {a0.x, a0.y, a0.z, a0.w, a1.x, a1.y, a1.z, a1.w};
      float bv[4] = {bf.x, bf.y, bf.z, bf.w};
      #pragma unroll
      for (int i = 0; i < 8; ++i)
        #pragma unroll
        for (int j = 0; j < 4; ++j) acc[i][j] = fmaf(a[i], bv[j], acc[i][j]);
    }
    __syncthreads();
  }

  float4 b2 = *(const float4*)&sb2[c4];
  float4 w3 = *(const float4*)&sW3[c4];
  #pragma unroll
  for (int i = 0; i < 8; ++i) {
    float s = fmaxf(acc[i][0] + b2.x, 0.f) * w3.x
            + fmaxf(acc[i][1] + b2.y, 0.f) * w3.y
            + fmaxf(acc[i][2] + b2.z, 0.f) * w3.z
            + fmaxf(acc[i][3] + b2.w, 0.f) * w3.w;
    red[(r8 + i) * 32 + (t & 31)] = s;
  }
  __syncthreads();
  if (t < 64) {
    float s = sb3[0];
    #pragma unroll
    for (int g = 0; g < 32; ++g) s += red[t * 32 + g];
    scores[row0 + t] = 1.f / (1.f + expf(-s));
  }
}

extern "C" void kernel_launch(void* const* d_in, const int* in_sizes, int n_in,
                              void* d_out, int out_size, void* d_ws, size_t ws_size,
                              hipStream_t stream) {
  const float* x    = (const float*)d_in[0];
  const float* gum  = (const float*)d_in[1];
  const float* gW1  = (const float*)d_in[2];
  const float* gb1  = (const float*)d_in[3];
  const float* ln1s = (const float*)d_in[4];
  const float* ln1b = (const float*)d_in[5];
  const float* gW2  = (const float*)d_in[6];
  const float* gb2  = (const float*)d_in[7];
  const float* ln2s = (const float*)d_in[8];
  const float* ln2b = (const float*)d_in[9];
  const float* gW3  = (const float*)d_in[10];
  const float* gb3  = (const float*)d_in[11];
  const float* sW1  = (const float*)d_in[12];
  const float* sb1  = (const float*)d_in[13];
  const float* sW2  = (const float*)d_in[14];
  const float* sb2  = (const float*)d_in[15];
  const float* sW3  = (const float*)d_in[16];
  const float* sb3  = (const float*)d_in[17];
  const float* yW1  = (const float*)d_in[18];
  const float* yb1  = (const float*)d_in[19];
  const float* yW2  = (const float*)d_in[20];
  const float* yb2  = (const float*)d_in[21];

  float* out    = (float*)d_out;
  float* probs  = out;
  float* scores = out + OFF_SCORES;
  float* syn    = out + OFF_SYN;
  float* logits = out + OFF_LOGITS;

  float* h2 = (float*)d_ws;                              // 128*256 f32 (131072 floats)
  float* t1 = (float*)((char*)d_ws + 131072 * 4);        // 12800*256 f32 = 13.1 MB

  gen_mlp_kernel<<<128, 256, 0, stream>>>(x, gW1, gb1, ln1s, ln1b, gW2, gb2, ln2s, ln2b, h2);
  gemm3_kernel<<<800, 256, 0, stream>>>(h2, gW3, gb3, logits);
  tail_kernel<<<12800, 256, 0, stream>>>(x, gum, sW1, sb1, yW1, yb1, yW2, yb2,
                                         logits, probs, syn, t1);
  scorer2_kernel<<<200, 256, 0, stream>>>(t1, sW2, sb2, sW3, sb3, scores);
}

// Round 6
// 508.746 us; speedup vs baseline: 1.2523x; 1.2523x over previous
//
#include <hip/hip_runtime.h>
#include <math.h>

// Shapes
#define B_   128
#define D_   1024
#define H_   256
#define M_   100
#define K_   5
#define MD   102400   // M_*D_
#define EPS_ 1e-5f

// d_out layout (f32): probs[128*100*1024], scores[12800], syn[12800], logits[128*100*1024]
#define OFF_SCORES 13107200
#define OFF_SYN    13120000
#define OFF_LOGITS 13132800

// ---------------- reduction helpers ----------------
__device__ __forceinline__ float block_sum(float v, float* red, int t) {
  #pragma unroll
  for (int off = 1; off < 64; off <<= 1) v += __shfl_xor(v, off);
  if ((t & 63) == 0) red[t >> 6] = v;
  __syncthreads();
  float s = red[0] + red[1] + red[2] + red[3];
  __syncthreads();
  return s;
}

__device__ __forceinline__ float block_max(float v, float* red, int t) {
  #pragma unroll
  for (int off = 1; off < 64; off <<= 1) v = fmaxf(v, __shfl_xor(v, off));
  if ((t & 63) == 0) red[t >> 6] = v;
  __syncthreads();
  float s = fmaxf(fmaxf(red[0], red[1]), fmaxf(red[2], red[3]));
  __syncthreads();
  return s;
}

__device__ __forceinline__ void block_sum2(float& a, float& b, float* red, int t) {
  #pragma unroll
  for (int off = 1; off < 64; off <<= 1) { a += __shfl_xor(a, off); b += __shfl_xor(b, off); }
  if ((t & 63) == 0) { red[(t >> 6) * 2] = a; red[(t >> 6) * 2 + 1] = b; }
  __syncthreads();
  a = red[0] + red[2] + red[4] + red[6];
  b = red[1] + red[3] + red[5] + red[7];
  __syncthreads();
}

// ---------------- K1: generator layers 1+2 (per batch row) ----------------
// Round-6: explicit 8-deep rolling load prefetch in both layers. Load issue
// order is free; fmaf accumulation order unchanged (d=0..1023 / h=0..511
// sequential) -> bit-identical h2.
__global__ __launch_bounds__(256) void gen_mlp_kernel(
    const float* __restrict__ x,
    const float* __restrict__ gW1, const float* __restrict__ gb1,
    const float* __restrict__ ln1s, const float* __restrict__ ln1b,
    const float* __restrict__ gW2, const float* __restrict__ gb2,
    const float* __restrict__ ln2s, const float* __restrict__ ln2b,
    float* __restrict__ h2out)
{
  __shared__ float xs[1024];
  __shared__ float h1s[512];
  __shared__ float red[8];
  int b = blockIdx.x, t = threadIdx.x;
  const float* xr = x + b * 1024;
  #pragma unroll
  for (int i = 0; i < 4; ++i) xs[t + i * 256] = xr[t + i * 256];
  __syncthreads();

  // layer1: thread computes outputs o=2t, 2t+1 (512 outputs), 8-deep prefetch
  float a0 = 0.f, a1 = 0.f;
  {
    float2 pre[8];
    #pragma unroll
    for (int j = 0; j < 8; ++j) pre[j] = *(const float2*)&gW1[j * 512 + 2 * t];
    #pragma unroll 1
    for (int d0 = 0; d0 < 1024; d0 += 8) {
      float2 cur[8];
      #pragma unroll
      for (int j = 0; j < 8; ++j) cur[j] = pre[j];
      if (d0 + 8 < 1024) {
        #pragma unroll
        for (int j = 0; j < 8; ++j)
          pre[j] = *(const float2*)&gW1[(d0 + 8 + j) * 512 + 2 * t];
      }
      #pragma unroll
      for (int j = 0; j < 8; ++j) {
        float xv = xs[d0 + j];
        a0 = fmaf(xv, cur[j].x, a0);
        a1 = fmaf(xv, cur[j].y, a1);
      }
    }
  }
  a0 += gb1[2 * t]; a1 += gb1[2 * t + 1];
  float s = a0 + a1, sq = a0 * a0 + a1 * a1;
  block_sum2(s, sq, red, t);
  float mu = s * (1.f / 512.f);
  float var = sq * (1.f / 512.f) - mu * mu;
  float inv = rsqrtf(var + EPS_);
  h1s[2 * t]     = fmaxf((a0 - mu) * inv * ln1s[2 * t]     + ln1b[2 * t],     0.f);
  h1s[2 * t + 1] = fmaxf((a1 - mu) * inv * ln1s[2 * t + 1] + ln1b[2 * t + 1], 0.f);
  __syncthreads();

  // layer2: thread computes output o=t (256 outputs), 8-deep prefetch
  float acc = 0.f;
  {
    float pre[8];
    #pragma unroll
    for (int j = 0; j < 8; ++j) pre[j] = gW2[j * 256 + t];
    #pragma unroll 1
    for (int h0 = 0; h0 < 512; h0 += 8) {
      float cur[8];
      #pragma unroll
      for (int j = 0; j < 8; ++j) cur[j] = pre[j];
      if (h0 + 8 < 512) {
        #pragma unroll
        for (int j = 0; j < 8; ++j) pre[j] = gW2[(h0 + 8 + j) * 256 + t];
      }
      #pragma unroll
      for (int j = 0; j < 8; ++j) acc = fmaf(h1s[h0 + j], cur[j], acc);
    }
  }
  acc += gb2[t];
  float s2 = acc, sq2 = acc * acc;
  block_sum2(s2, sq2, red, t);
  float mu2 = s2 * (1.f / 256.f);
  float var2 = sq2 * (1.f / 256.f) - mu2 * mu2;
  float inv2 = rsqrtf(var2 + EPS_);
  h2out[b * 256 + t] = fmaxf((acc - mu2) * inv2 * ln2s[t] + ln2b[t], 0.f);
}

// ---------------- K2: logits = h2 @ gW3 + gb3  (128 x 102400, K=256) ----------------
// Round-4 verified version (118 us, FETCH/WRITE at ideal 52/51 MB): DMA-
// pipelined GEMM. W streamed via global_load_lds (vmcnt-tracked, zero
// VGPR/SGPR cost) into a double-buffered LDS tile; 2-phase raw-barrier
// schedule. Next tile's W-DMA + h2 loads issue before the compute phase,
// flying under ~2000cy of FMA. kk order 0..255 sequential -> bit-identical.
__global__ __launch_bounds__(256, 3) void gemm3_kernel(
    const float* __restrict__ h2, const float* __restrict__ gW3,
    const float* __restrict__ gb3, float* __restrict__ logits)
{
  __shared__ float h2t[32 * 132];       // A tile: [kk][row], stride 132
  __shared__ float Wlds[2 * 32 * 128];  // B tiles: dbuf [kk][col], lane-linear for DMA
  int t = threadIdx.x;
  int lane = t & 63;
  int w = t >> 6;                       // wave id 0..3
  int rg8 = (t >> 4) * 8;               // row-group base 0..120
  int cg4 = (t & 15) * 4;               // col-frag base 0..60
  long col0 = (long)blockIdx.x * 128;

  int bb = t >> 1;                      // h2 staging: row 0..127
  int ks = (t & 1) * 16;                // h2 staging: kk offset 0 or 16

  int krl = lane >> 5;                  // DMA: sub-row 0/1
  int cid = (lane & 31) * 4;            // DMA: col float offset

  float acc[8][8];
  #pragma unroll
  for (int i = 0; i < 8; ++i)
    #pragma unroll
    for (int j = 0; j < 8; ++j) acc[i][j] = 0.f;

  // ---- prologue: issue W(0) DMA + h2(0) register loads ----
  #pragma unroll
  for (int p = 0; p < 4; ++p) {
    int kkrow = p * 8 + w * 2;          // wave-uniform
    const float* g = gW3 + (long)(kkrow + krl) * MD + col0 + cid;
    float* l = &Wlds[kkrow * 128];
    __builtin_amdgcn_global_load_lds(
        (const __attribute__((address_space(1))) void*)g,
        (__attribute__((address_space(3))) void*)l, 16, 0, 0);
  }
  const float* hp = &h2[bb * 256 + ks];
  float4 ha = *(const float4*)(hp + 0);
  float4 hb = *(const float4*)(hp + 4);
  float4 hc = *(const float4*)(hp + 8);
  float4 hd = *(const float4*)(hp + 12);

  #pragma unroll 1
  for (int kt = 0; kt < 8; ++kt) {
    // wait: this tile's W DMA landed in LDS, h2 regs arrived
    asm volatile("s_waitcnt vmcnt(0)" ::: "memory");
    __builtin_amdgcn_s_barrier();       // all waves' DMA done, prev compute done

    // write h2 tile (transposed) into LDS
    {
      float vals[16] = {ha.x, ha.y, ha.z, ha.w, hb.x, hb.y, hb.z, hb.w,
                        hc.x, hc.y, hc.z, hc.w, hd.x, hd.y, hd.z, hd.w};
      #pragma unroll
      for (int j = 0; j < 16; ++j) h2t[(ks + j) * 132 + bb] = vals[j];
    }

    // issue NEXT tile's W DMA + h2 loads (they fly under the compute below)
    if (kt + 1 < 8) {
      #pragma unroll
      for (int p = 0; p < 4; ++p) {
        int kkrow = p * 8 + w * 2;
        const float* g = gW3 + ((long)(kt + 1) * 32 + kkrow + krl) * MD + col0 + cid;
        float* l = &Wlds[((kt + 1) & 1) * 4096 + kkrow * 128];
        __builtin_amdgcn_global_load_lds(
            (const __attribute__((address_space(1))) void*)g,
            (__attribute__((address_space(3))) void*)l, 16, 0, 0);
      }
      const float* hq = &h2[bb * 256 + (kt + 1) * 32 + ks];
      ha = *(const float4*)(hq + 0);
      hb = *(const float4*)(hq + 4);
      hc = *(const float4*)(hq + 8);
      hd = *(const float4*)(hq + 12);
    }

    asm volatile("s_waitcnt lgkmcnt(0)" ::: "memory");  // my h2t writes done
    __builtin_amdgcn_s_barrier();                        // all waves' h2t visible

    // compute this tile
    const float* Wb = &Wlds[(kt & 1) * 4096];
    #pragma unroll 8
    for (int kk = 0; kk < 32; ++kk) {
      float4 a0 = *(const float4*)&h2t[kk * 132 + rg8];
      float4 a1 = *(const float4*)&h2t[kk * 132 + rg8 + 4];
      float4 b0 = *(const float4*)&Wb[kk * 128 + cg4];
      float4 b1 = *(const float4*)&Wb[kk * 128 + 64 + cg4];
      float a[8] = {a0.x, a0.y, a0.z, a0.w, a1.x, a1.y, a1.z, a1.w};
      float bv[8] = {b0.x, b0.y, b0.z, b0.w, b1.x, b1.y, b1.z, b1.w};
      #pragma unroll
      for (int i = 0; i < 8; ++i)
        #pragma unroll
        for (int j = 0; j < 8; ++j)
          acc[i][j] = fmaf(a[i], bv[j], acc[i][j]);
    }
  }

  // epilogue: bias + store (cols cg4..cg4+3 and 64+cg4..64+cg4+3)
  float4 bias0 = *(const float4*)&gb3[col0 + cg4];
  float4 bias1 = *(const float4*)&gb3[col0 + 64 + cg4];
  #pragma unroll
  for (int i = 0; i < 8; ++i) {
    long row = rg8 + i;
    float4 o0, o1;
    o0.x = acc[i][0] + bias0.x; o0.y = acc[i][1] + bias0.y;
    o0.z = acc[i][2] + bias0.z; o0.w = acc[i][3] + bias0.w;
    o1.x = acc[i][4] + bias1.x; o1.y = acc[i][5] + bias1.y;
    o1.z = acc[i][6] + bias1.z; o1.w = acc[i][7] + bias1.w;
    *(float4*)&logits[row * MD + col0 + cg4] = o0;
    *(float4*)&logits[row * MD + col0 + 64 + cg4] = o1;
  }
}

// ---------------- K3: softmax + top-5 + gathers + synergy + t1 (per (b,m) row) ----------------
// Round-0 verified version (round-5 restructure was neutral-to-negative).
__global__ __launch_bounds__(256) void tail_kernel(
    const float* __restrict__ x, const float* __restrict__ gumbel,
    const float* __restrict__ sW1, const float* __restrict__ sb1,
    const float* __restrict__ yW1, const float* __restrict__ yb1,
    const float* __restrict__ yW2, const float* __restrict__ yb2,
    const float* __restrict__ logits, float* __restrict__ probs,
    float* __restrict__ syn, float* __restrict__ t1ws)
{
  __shared__ float red[8];
  __shared__ float redv[4];
  __shared__ int   redi[4];
  __shared__ int   winner;
  int row = blockIdx.x;       // row = b*100 + m
  int t = threadIdx.x;
  int b = row / 100;
  const float* lg = logits + row * 1024;
  const float* gm = gumbel + row * 1024;

  // z = (logit + gumbel) / tau, tau = 0.5
  float z[4];
  #pragma unroll
  for (int i = 0; i < 4; ++i) z[i] = (lg[t + i * 256] + gm[t + i * 256]) * 2.0f;
  float mx = fmaxf(fmaxf(z[0], z[1]), fmaxf(z[2], z[3]));
  mx = block_max(mx, red, t);
  float p[4]; float ls = 0.f;
  #pragma unroll
  for (int i = 0; i < 4; ++i) { p[i] = expf(z[i] - mx); ls += p[i]; }
  float denom = block_sum(ls, red, t);
  float inv = 1.f / denom;
  float v[4];
  #pragma unroll
  for (int i = 0; i < 4; ++i) {
    v[i] = p[i] * inv;
    probs[row * 1024 + t + i * 256] = v[i];
  }

  // top-5 on written prob values; tie-break: lower index first (jax.lax.top_k stable order)
  float t1acc = sb1[t];
  float u1acc = yb1[t];
  for (int jsel = 0; jsel < 5; ++jsel) {
    float bv = v[0]; int bi = t;          // idx = i*256 + t
    #pragma unroll
    for (int i = 1; i < 4; ++i) {
      int idx = i * 256 + t;
      if (v[i] > bv || (v[i] == bv && idx < bi)) { bv = v[i]; bi = idx; }
    }
    #pragma unroll
    for (int off = 1; off < 64; off <<= 1) {
      float ov = __shfl_xor(bv, off);
      int oi = __shfl_xor(bi, off);
      if (ov > bv || (ov == bv && oi < bi)) { bv = ov; bi = oi; }
    }
    if ((t & 63) == 0) { redv[t >> 6] = bv; redi[t >> 6] = bi; }
    __syncthreads();
    if (t == 0) {
      float wv = redv[0]; int wi = redi[0];
      #pragma unroll
      for (int w = 1; w < 4; ++w)
        if (redv[w] > wv || (redv[w] == wv && redi[w] < wi)) { wv = redv[w]; wi = redi[w]; }
      winner = wi;
    }
    __syncthreads();
    int w = winner;
    if ((w & 255) == t) v[w >> 8] = -1.f;   // mask selected
    float xv = x[b * 1024 + w];             // uniform (scalar) load
    t1acc = fmaf(xv, sW1[(jsel * 1024 + w) * 256 + t], t1acc);
    u1acc = fmaf(xv, yW1[(jsel * 1024 + w) * 256 + t], u1acc);
    __syncthreads();
  }

  float t1v = fmaxf(t1acc, 0.f);
  float u1v = fmaxf(u1acc, 0.f);
  t1ws[row * 256 + t] = t1v;

  // synergy = tanh(u1 . yW2 + yb2)
  float part = u1v * yW2[t];
  float dsum = block_sum(part, red, t);
  if (t == 0) syn[row] = tanhf(dsum + yb2[0]);
}

// ---------------- K4: scores = sigmoid(relu(t1 @ sW2 + sb2) @ sW3 + sb3) ----------------
// Round-6: 32 rows/block -> 400 blocks (was 200 at 1 block/CU, zero TLP).
// Thread = 4 rows x 4 cols; per-output kk accumulation order (0..255) and
// group-sum order unchanged -> bit-identical scores.
__global__ __launch_bounds__(256) void scorer2_kernel(
    const float* __restrict__ t1, const float* __restrict__ sW2,
    const float* __restrict__ sb2, const float* __restrict__ sW3,
    const float* __restrict__ sb3, float* __restrict__ scores)
{
  __shared__ float t1t[64 * 36];   // [kk][row], 32 rows, stride 36 (144B rows, 16B-aligned)
  __shared__ float red[32 * 32];   // [colgroup][row]
  int t = threadIdx.x;
  int row0 = blockIdx.x * 32;
  int c4 = (t & 31) * 4;           // col base 0..124
  int r4 = (t >> 5) * 4;           // row base 0..28
  float acc[4][4];
  #pragma unroll
  for (int i = 0; i < 4; ++i)
    #pragma unroll
    for (int j = 0; j < 4; ++j) acc[i][j] = 0.f;

  for (int c = 0; c < 4; ++c) {
    // stage t1[row0..row0+31, c*64..c*64+63] transposed (coalesced reads)
    #pragma unroll
    for (int p = 0; p < 8; ++p) {
      int rr = p * 4 + (t >> 6);
      int kk = t & 63;
      t1t[kk * 36 + rr] = t1[(row0 + rr) * 256 + c * 64 + kk];
    }
    __syncthreads();
    #pragma unroll 4
    for (int kk = 0; kk < 64; ++kk) {
      float4 bf = *(const float4*)&sW2[(c * 64 + kk) * 128 + c4];
      float4 a0 = *(const float4*)&t1t[kk * 36 + r4];
      float a[4] = {a0.x, a0.y, a0.z, a0.w};
      float bv[4] = {bf.x, bf.y, bf.z, bf.w};
      #pragma unroll
      for (int i = 0; i < 4; ++i)
        #pragma unroll
        for (int j = 0; j < 4; ++j) acc[i][j] = fmaf(a[i], bv[j], acc[i][j]);
    }
    __syncthreads();
  }

  float4 b2 = *(const float4*)&sb2[c4];
  float4 w3 = *(const float4*)&sW3[c4];
  #pragma unroll
  for (int i = 0; i < 4; ++i) {
    float s = fmaxf(acc[i][0] + b2.x, 0.f) * w3.x
            + fmaxf(acc[i][1] + b2.y, 0.f) * w3.y
            + fmaxf(acc[i][2] + b2.z, 0.f) * w3.z
            + fmaxf(acc[i][3] + b2.w, 0.f) * w3.w;
    red[(t & 31) * 32 + (r4 + i)] = s;   // [colgroup][row]: conflict-free final reads
  }
  __syncthreads();
  if (t < 32) {
    float s = sb3[0];
    #pragma unroll
    for (int g = 0; g < 32; ++g) s += red[g * 32 + t];
    scores[row0 + t] = 1.f / (1.f + expf(-s));
  }
}

extern "C" void kernel_launch(void* const* d_in, const int* in_sizes, int n_in,
                              void* d_out, int out_size, void* d_ws, size_t ws_size,
                              hipStream_t stream) {
  const float* x    = (const float*)d_in[0];
  const float* gum  = (const float*)d_in[1];
  const float* gW1  = (const float*)d_in[2];
  const float* gb1  = (const float*)d_in[3];
  const float* ln1s = (const float*)d_in[4];
  const float* ln1b = (const float*)d_in[5];
  const float* gW2  = (const float*)d_in[6];
  const float* gb2  = (const float*)d_in[7];
  const float* ln2s = (const float*)d_in[8];
  const float* ln2b = (const float*)d_in[9];
  const float* gW3  = (const float*)d_in[10];
  const float* gb3  = (const float*)d_in[11];
  const float* sW1  = (const float*)d_in[12];
  const float* sb1  = (const float*)d_in[13];
  const float* sW2  = (const float*)d_in[14];
  const float* sb2  = (const float*)d_in[15];
  const float* sW3  = (const float*)d_in[16];
  const float* sb3  = (const float*)d_in[17];
  const float* yW1  = (const float*)d_in[18];
  const float* yb1  = (const float*)d_in[19];
  const float* yW2  = (const float*)d_in[20];
  const float* yb2  = (const float*)d_in[21];

  float* out    = (float*)d_out;
  float* probs  = out;
  float* scores = out + OFF_SCORES;
  float* syn    = out + OFF_SYN;
  float* logits = out + OFF_LOGITS;

  float* h2 = (float*)d_ws;                              // 128*256 f32 (131072 floats)
  float* t1 = (float*)((char*)d_ws + 131072 * 4);        // 12800*256 f32 = 13.1 MB

  gen_mlp_kernel<<<128, 256, 0, stream>>>(x, gW1, gb1, ln1s, ln1b, gW2, gb2, ln2s, ln2b, h2);
  gemm3_kernel<<<800, 256, 0, stream>>>(h2, gW3, gb3, logits);
  tail_kernel<<<12800, 256, 0, stream>>>(x, gum, sW1, sb1, yW1, yb1, yW2, yb2,
                                         logits, probs, syn, t1);
  scorer2_kernel<<<400, 256, 0, stream>>>(t1, sW2, sb2, sW3, sb3, scores);
}

// Round 7
// 448.646 us; speedup vs baseline: 1.4200x; 1.1340x over previous
//
#include <hip/hip_runtime.h>
#include <math.h>

// Shapes
#define B_   128
#define D_   1024
#define H_   256
#define M_   100
#define K_   5
#define MD   102400   // M_*D_
#define EPS_ 1e-5f

// d_out layout (f32): probs[128*100*1024], scores[12800], syn[12800], logits[128*100*1024]
#define OFF_SCORES 13107200
#define OFF_SYN    13120000
#define OFF_LOGITS 13132800

// ---------------- reduction helpers ----------------
__device__ __forceinline__ float block_sum(float v, float* red, int t) {
  #pragma unroll
  for (int off = 1; off < 64; off <<= 1) v += __shfl_xor(v, off);
  if ((t & 63) == 0) red[t >> 6] = v;
  __syncthreads();
  float s = red[0] + red[1] + red[2] + red[3];
  __syncthreads();
  return s;
}

__device__ __forceinline__ void block_sum2(float& a, float& b, float* red, int t) {
  #pragma unroll
  for (int off = 1; off < 64; off <<= 1) { a += __shfl_xor(a, off); b += __shfl_xor(b, off); }
  if ((t & 63) == 0) { red[(t >> 6) * 2] = a; red[(t >> 6) * 2 + 1] = b; }
  __syncthreads();
  a = red[0] + red[2] + red[4] + red[6];
  b = red[1] + red[3] + red[5] + red[7];
  __syncthreads();
}

// ---------------- K1: generator layers 1+2 (per batch row) ----------------
// Round-0 verified version (round-6 prefetch variant regressed).
__global__ __launch_bounds__(256) void gen_mlp_kernel(
    const float* __restrict__ x,
    const float* __restrict__ gW1, const float* __restrict__ gb1,
    const float* __restrict__ ln1s, const float* __restrict__ ln1b,
    const float* __restrict__ gW2, const float* __restrict__ gb2,
    const float* __restrict__ ln2s, const float* __restrict__ ln2b,
    float* __restrict__ h2out)
{
  __shared__ float xs[1024];
  __shared__ float h1s[512];
  __shared__ float red[8];
  int b = blockIdx.x, t = threadIdx.x;
  const float* xr = x + b * 1024;
  #pragma unroll
  for (int i = 0; i < 4; ++i) xs[t + i * 256] = xr[t + i * 256];
  __syncthreads();

  // layer1: thread computes outputs o=2t, 2t+1 (512 outputs)
  float a0 = 0.f, a1 = 0.f;
  for (int d = 0; d < 1024; ++d) {
    float xv = xs[d];
    float2 w = *(const float2*)&gW1[d * 512 + 2 * t];
    a0 = fmaf(xv, w.x, a0);
    a1 = fmaf(xv, w.y, a1);
  }
  a0 += gb1[2 * t]; a1 += gb1[2 * t + 1];
  float s = a0 + a1, sq = a0 * a0 + a1 * a1;
  block_sum2(s, sq, red, t);
  float mu = s * (1.f / 512.f);
  float var = sq * (1.f / 512.f) - mu * mu;
  float inv = rsqrtf(var + EPS_);
  h1s[2 * t]     = fmaxf((a0 - mu) * inv * ln1s[2 * t]     + ln1b[2 * t],     0.f);
  h1s[2 * t + 1] = fmaxf((a1 - mu) * inv * ln1s[2 * t + 1] + ln1b[2 * t + 1], 0.f);
  __syncthreads();

  // layer2: thread computes output o=t (256 outputs)
  float acc = 0.f;
  for (int h = 0; h < 512; ++h) acc = fmaf(h1s[h], gW2[h * 256 + t], acc);
  acc += gb2[t];
  float s2 = acc, sq2 = acc * acc;
  block_sum2(s2, sq2, red, t);
  float mu2 = s2 * (1.f / 256.f);
  float var2 = sq2 * (1.f / 256.f) - mu2 * mu2;
  float inv2 = rsqrtf(var2 + EPS_);
  h2out[b * 256 + t] = fmaxf((acc - mu2) * inv2 * ln2s[t] + ln2b[t], 0.f);
}

// ---------------- K2: logits = h2 @ gW3 + gb3  (128 x 102400, K=256) ----------------
// Round-4 verified version (118 us, FETCH/WRITE at ideal 52/51 MB): DMA-
// pipelined GEMM via global_load_lds + raw barriers. Do not modify without
// checking WRITE_SIZE stays ~51 MB (spill tell) and VGPR ~68.
__global__ __launch_bounds__(256, 3) void gemm3_kernel(
    const float* __restrict__ h2, const float* __restrict__ gW3,
    const float* __restrict__ gb3, float* __restrict__ logits)
{
  __shared__ float h2t[32 * 132];       // A tile: [kk][row], stride 132
  __shared__ float Wlds[2 * 32 * 128];  // B tiles: dbuf [kk][col], lane-linear for DMA
  int t = threadIdx.x;
  int lane = t & 63;
  int w = t >> 6;                       // wave id 0..3
  int rg8 = (t >> 4) * 8;               // row-group base 0..120
  int cg4 = (t & 15) * 4;               // col-frag base 0..60
  long col0 = (long)blockIdx.x * 128;

  int bb = t >> 1;                      // h2 staging: row 0..127
  int ks = (t & 1) * 16;                // h2 staging: kk offset 0 or 16

  int krl = lane >> 5;                  // DMA: sub-row 0/1
  int cid = (lane & 31) * 4;            // DMA: col float offset

  float acc[8][8];
  #pragma unroll
  for (int i = 0; i < 8; ++i)
    #pragma unroll
    for (int j = 0; j < 8; ++j) acc[i][j] = 0.f;

  // ---- prologue: issue W(0) DMA + h2(0) register loads ----
  #pragma unroll
  for (int p = 0; p < 4; ++p) {
    int kkrow = p * 8 + w * 2;          // wave-uniform
    const float* g = gW3 + (long)(kkrow + krl) * MD + col0 + cid;
    float* l = &Wlds[kkrow * 128];
    __builtin_amdgcn_global_load_lds(
        (const __attribute__((address_space(1))) void*)g,
        (__attribute__((address_space(3))) void*)l, 16, 0, 0);
  }
  const float* hp = &h2[bb * 256 + ks];
  float4 ha = *(const float4*)(hp + 0);
  float4 hb = *(const float4*)(hp + 4);
  float4 hc = *(const float4*)(hp + 8);
  float4 hd = *(const float4*)(hp + 12);

  #pragma unroll 1
  for (int kt = 0; kt < 8; ++kt) {
    // wait: this tile's W DMA landed in LDS, h2 regs arrived
    asm volatile("s_waitcnt vmcnt(0)" ::: "memory");
    __builtin_amdgcn_s_barrier();       // all waves' DMA done, prev compute done

    // write h2 tile (transposed) into LDS
    {
      float vals[16] = {ha.x, ha.y, ha.z, ha.w, hb.x, hb.y, hb.z, hb.w,
                        hc.x, hc.y, hc.z, hc.w, hd.x, hd.y, hd.z, hd.w};
      #pragma unroll
      for (int j = 0; j < 16; ++j) h2t[(ks + j) * 132 + bb] = vals[j];
    }

    // issue NEXT tile's W DMA + h2 loads (they fly under the compute below)
    if (kt + 1 < 8) {
      #pragma unroll
      for (int p = 0; p < 4; ++p) {
        int kkrow = p * 8 + w * 2;
        const float* g = gW3 + ((long)(kt + 1) * 32 + kkrow + krl) * MD + col0 + cid;
        float* l = &Wlds[((kt + 1) & 1) * 4096 + kkrow * 128];
        __builtin_amdgcn_global_load_lds(
            (const __attribute__((address_space(1))) void*)g,
            (__attribute__((address_space(3))) void*)l, 16, 0, 0);
      }
      const float* hq = &h2[bb * 256 + (kt + 1) * 32 + ks];
      ha = *(const float4*)(hq + 0);
      hb = *(const float4*)(hq + 4);
      hc = *(const float4*)(hq + 8);
      hd = *(const float4*)(hq + 12);
    }

    asm volatile("s_waitcnt lgkmcnt(0)" ::: "memory");  // my h2t writes done
    __builtin_amdgcn_s_barrier();                        // all waves' h2t visible

    // compute this tile
    const float* Wb = &Wlds[(kt & 1) * 4096];
    #pragma unroll 8
    for (int kk = 0; kk < 32; ++kk) {
      float4 a0 = *(const float4*)&h2t[kk * 132 + rg8];
      float4 a1 = *(const float4*)&h2t[kk * 132 + rg8 + 4];
      float4 b0 = *(const float4*)&Wb[kk * 128 + cg4];
      float4 b1 = *(const float4*)&Wb[kk * 128 + 64 + cg4];
      float a[8] = {a0.x, a0.y, a0.z, a0.w, a1.x, a1.y, a1.z, a1.w};
      float bv[8] = {b0.x, b0.y, b0.z, b0.w, b1.x, b1.y, b1.z, b1.w};
      #pragma unroll
      for (int i = 0; i < 8; ++i)
        #pragma unroll
        for (int j = 0; j < 8; ++j)
          acc[i][j] = fmaf(a[i], bv[j], acc[i][j]);
    }
  }

  // epilogue: bias + store (cols cg4..cg4+3 and 64+cg4..64+cg4+3)
  float4 bias0 = *(const float4*)&gb3[col0 + cg4];
  float4 bias1 = *(const float4*)&gb3[col0 + 64 + cg4];
  #pragma unroll
  for (int i = 0; i < 8; ++i) {
    long row = rg8 + i;
    float4 o0, o1;
    o0.x = acc[i][0] + bias0.x; o0.y = acc[i][1] + bias0.y;
    o0.z = acc[i][2] + bias0.z; o0.w = acc[i][3] + bias0.w;
    o1.x = acc[i][4] + bias1.x; o1.y = acc[i][5] + bias1.y;
    o1.z = acc[i][6] + bias1.z; o1.w = acc[i][7] + bias1.w;
    *(float4*)&logits[row * MD + col0 + cg4] = o0;
    *(float4*)&logits[row * MD + col0 + 64 + cg4] = o1;
  }
}

// ---------------- K3: softmax + top-5 + gathers + synergy + t1 ----------------
// Round-7: ONE WAVE PER ROW, zero barriers, zero LDS. 16 elems/lane
// (4 x float4). Softmax max/sum, top-5 select+broadcast all via 6-step
// __shfl_xor butterflies. Selection round jsel+1 is independent of jsel's
// gather loads -> all 10 sW1/yW1 row gathers overlap in flight.
// Winner set identical to round-0 (same tie-break); t1acc fmaf order per
// output unchanged (sb1 then jsel 0..4) -> t1/scores bit-identical given
// same winners. denom/synergy reduction tree differs by ~1 ulp (tolerated).
__global__ __launch_bounds__(256) void tail_kernel(
    const float* __restrict__ x, const float* __restrict__ gumbel,
    const float* __restrict__ sW1, const float* __restrict__ sb1,
    const float* __restrict__ yW1, const float* __restrict__ yb1,
    const float* __restrict__ yW2, const float* __restrict__ yb2,
    const float* __restrict__ logits, float* __restrict__ probs,
    float* __restrict__ syn, float* __restrict__ t1ws)
{
  int t = threadIdx.x;
  int lane = t & 63;
  int wid = t >> 6;
  int row = blockIdx.x * 4 + wid;      // 3200 blocks x 4 waves
  int b = row / 100;
  int c4 = lane * 4;                   // this lane's element base within a 256-chunk
  const float* lg = logits + row * 1024;
  const float* gm = gumbel + row * 1024;

  // z = (logit + gumbel)/tau; element of v[i] comp j has global idx i*256+c4+j
  float4 v[4];
  #pragma unroll
  for (int i = 0; i < 4; ++i) {
    float4 a = *(const float4*)&lg[i * 256 + c4];
    float4 g = *(const float4*)&gm[i * 256 + c4];
    v[i].x = (a.x + g.x) * 2.0f;
    v[i].y = (a.y + g.y) * 2.0f;
    v[i].z = (a.z + g.z) * 2.0f;
    v[i].w = (a.w + g.w) * 2.0f;
  }

  // wave max (exact, order-free)
  float mx = v[0].x;
  #pragma unroll
  for (int i = 0; i < 4; ++i) {
    mx = fmaxf(mx, fmaxf(fmaxf(v[i].x, v[i].y), fmaxf(v[i].z, v[i].w)));
  }
  #pragma unroll
  for (int off = 1; off < 64; off <<= 1) mx = fmaxf(mx, __shfl_xor(mx, off));

  // exp + wave sum
  float ls = 0.f;
  #pragma unroll
  for (int i = 0; i < 4; ++i) {
    v[i].x = expf(v[i].x - mx); ls += v[i].x;
    v[i].y = expf(v[i].y - mx); ls += v[i].y;
    v[i].z = expf(v[i].z - mx); ls += v[i].z;
    v[i].w = expf(v[i].w - mx); ls += v[i].w;
  }
  #pragma unroll
  for (int off = 1; off < 64; off <<= 1) ls += __shfl_xor(ls, off);
  float inv = 1.f / ls;

  #pragma unroll
  for (int i = 0; i < 4; ++i) {
    v[i].x *= inv; v[i].y *= inv; v[i].z *= inv; v[i].w *= inv;
    *(float4*)&probs[row * 1024 + i * 256 + c4] = v[i];
  }

  // ---- top-5, gathers fully overlapped ----
  const float* xb = x + b * 1024;
  float4 t1a = *(const float4*)&sb1[c4 & 255];   // c4 < 256 anyway
  float4 u1a = *(const float4*)&yb1[c4];

  #pragma unroll
  for (int jsel = 0; jsel < 5; ++jsel) {
    // local best of 16 (tie-break: lower idx) — static unroll
    float bv = v[0].x; int bi = 0 * 256 + c4 + 0;
    #pragma unroll
    for (int i = 0; i < 4; ++i) {
      float cv[4] = {v[i].x, v[i].y, v[i].z, v[i].w};
      #pragma unroll
      for (int j = 0; j < 4; ++j) {
        int idx = i * 256 + c4 + j;
        if (cv[j] > bv || (cv[j] == bv && idx < bi)) { bv = cv[j]; bi = idx; }
      }
    }
    // wave argmax butterfly
    #pragma unroll
    for (int off = 1; off < 64; off <<= 1) {
      float ov = __shfl_xor(bv, off);
      int oi = __shfl_xor(bi, off);
      if (ov > bv || (ov == bv && oi < bi)) { bv = ov; bi = oi; }
    }
    int wi = bi;                          // converged: same in all lanes

    // mask winner (static component indexing)
    #pragma unroll
    for (int i = 0; i < 4; ++i) {
      if (wi == i * 256 + c4 + 0) v[i].x = -1.f;
      if (wi == i * 256 + c4 + 1) v[i].y = -1.f;
      if (wi == i * 256 + c4 + 2) v[i].z = -1.f;
      if (wi == i * 256 + c4 + 3) v[i].w = -1.f;
    }

    // gathers: x scalar + 1KB coalesced rows of sW1/yW1
    float xv = xb[wi];
    float4 sw = *(const float4*)&sW1[(jsel * 1024 + wi) * 256 + c4];
    float4 yw = *(const float4*)&yW1[(jsel * 1024 + wi) * 256 + c4];
    t1a.x = fmaf(xv, sw.x, t1a.x); t1a.y = fmaf(xv, sw.y, t1a.y);
    t1a.z = fmaf(xv, sw.z, t1a.z); t1a.w = fmaf(xv, sw.w, t1a.w);
    u1a.x = fmaf(xv, yw.x, u1a.x); u1a.y = fmaf(xv, yw.y, u1a.y);
    u1a.z = fmaf(xv, yw.z, u1a.z); u1a.w = fmaf(xv, yw.w, u1a.w);
  }

  float4 t1v;
  t1v.x = fmaxf(t1a.x, 0.f); t1v.y = fmaxf(t1a.y, 0.f);
  t1v.z = fmaxf(t1a.z, 0.f); t1v.w = fmaxf(t1a.w, 0.f);
  *(float4*)&t1ws[row * 256 + c4] = t1v;

  float4 u1v;
  u1v.x = fmaxf(u1a.x, 0.f); u1v.y = fmaxf(u1a.y, 0.f);
  u1v.z = fmaxf(u1a.z, 0.f); u1v.w = fmaxf(u1a.w, 0.f);

  // synergy = tanh(u1 . yW2 + yb2), wave reduction
  float4 w2 = *(const float4*)&yW2[c4];
  float part = u1v.x * w2.x + u1v.y * w2.y + u1v.z * w2.z + u1v.w * w2.w;
  #pragma unroll
  for (int off = 1; off < 64; off <<= 1) part += __shfl_xor(part, off);
  if (lane == 0) syn[row] = tanhf(part + yb2[0]);
}

// ---------------- K4: scores = sigmoid(relu(t1 @ sW2 + sb2) @ sW3 + sb3) ----------------
// Round-0 verified version. Block = 64 rows x 128 cols, K=256.
__global__ __launch_bounds__(256) void scorer2_kernel(
    const float* __restrict__ t1, const float* __restrict__ sW2,
    const float* __restrict__ sb2, const float* __restrict__ sW3,
    const float* __restrict__ sb3, float* __restrict__ scores)
{
  __shared__ float t1t[64 * 68];   // [kk][row], stride 68 (16B-aligned)
  __shared__ float red[64 * 32];
  int t = threadIdx.x;
  int row0 = blockIdx.x * 64;
  int c4 = (t & 31) * 4;
  int r8 = (t >> 5) * 8;
  float acc[8][4];
  #pragma unroll
  for (int i = 0; i < 8; ++i)
    #pragma unroll
    for (int j = 0; j < 4; ++j) acc[i][j] = 0.f;

  for (int c = 0; c < 4; ++c) {
    #pragma unroll
    for (int p = 0; p < 16; ++p) {
      int rr = p * 4 + (t >> 6);
      int kk = t & 63;
      t1t[kk * 68 + rr] = t1[(row0 + rr) * 256 + c * 64 + kk];
    }
    __syncthreads();
    #pragma unroll 4
    for (int kk = 0; kk < 64; ++kk) {
      float4 bf = *(const float4*)&sW2[(c * 64 + kk) * 128 + c4];
      float4 a0 = *(const float4*)&t1t[kk * 68 + r8];
      float4 a1 = *(const float4*)&t1t[kk * 68 + r8 + 4];
      float a[8] = {a0.x, a0.y, a0.z, a0.w, a1.x, a1.y, a1.z, a1.w};
      float bv[4] = {bf.x, bf.y, bf.z, bf.w};
      #pragma unroll
      for (int i = 0; i < 8; ++i)
        #pragma unroll
        for (int j = 0; j < 4; ++j) acc[i][j] = fmaf(a[i], bv[j], acc[i][j]);
    }
    __syncthreads();
  }

  float4 b2 = *(const float4*)&sb2[c4];
  float4 w3 = *(const float4*)&sW3[c4];
  #pragma unroll
  for (int i = 0; i < 8; ++i) {
    float s = fmaxf(acc[i][0] + b2.x, 0.f) * w3.x
            + fmaxf(acc[i][1] + b2.y, 0.f) * w3.y
            + fmaxf(acc[i][2] + b2.z, 0.f) * w3.z
            + fmaxf(acc[i][3] + b2.w, 0.f) * w3.w;
    red[(r8 + i) * 32 + (t & 31)] = s;
  }
  __syncthreads();
  if (t < 64) {
    float s = sb3[0];
    #pragma unroll
    for (int g = 0; g < 32; ++g) s += red[t * 32 + g];
    scores[row0 + t] = 1.f / (1.f + expf(-s));
  }
}

extern "C" void kernel_launch(void* const* d_in, const int* in_sizes, int n_in,
                              void* d_out, int out_size, void* d_ws, size_t ws_size,
                              hipStream_t stream) {
  const float* x    = (const float*)d_in[0];
  const float* gum  = (const float*)d_in[1];
  const float* gW1  = (const float*)d_in[2];
  const float* gb1  = (const float*)d_in[3];
  const float* ln1s = (const float*)d_in[4];
  const float* ln1b = (const float*)d_in[5];
  const float* gW2  = (const float*)d_in[6];
  const float* gb2  = (const float*)d_in[7];
  const float* ln2s = (const float*)d_in[8];
  const float* ln2b = (const float*)d_in[9];
  const float* gW3  = (const float*)d_in[10];
  const float* gb3  = (const float*)d_in[11];
  const float* sW1  = (const float*)d_in[12];
  const float* sb1  = (const float*)d_in[13];
  const float* sW2  = (const float*)d_in[14];
  const float* sb2  = (const float*)d_in[15];
  const float* sW3  = (const float*)d_in[16];
  const float* sb3  = (const float*)d_in[17];
  const float* yW1  = (const float*)d_in[18];
  const float* yb1  = (const float*)d_in[19];
  const float* yW2  = (const float*)d_in[20];
  const float* yb2  = (const float*)d_in[21];

  float* out    = (float*)d_out;
  float* probs  = out;
  float* scores = out + OFF_SCORES;
  float* syn    = out + OFF_SYN;
  float* logits = out + OFF_LOGITS;

  float* h2 = (float*)d_ws;                              // 128*256 f32 (131072 floats)
  float* t1 = (float*)((char*)d_ws + 131072 * 4);        // 12800*256 f32 = 13.1 MB

  gen_mlp_kernel<<<128, 256, 0, stream>>>(x, gW1, gb1, ln1s, ln1b, gW2, gb2, ln2s, ln2b, h2);
  gemm3_kernel<<<800, 256, 0, stream>>>(h2, gW3, gb3, logits);
  tail_kernel<<<3200, 256, 0, stream>>>(x, gum, sW1, sb1, yW1, yb1, yW2, yb2,
                                        logits, probs, syn, t1);
  scorer2_kernel<<<200, 256, 0, stream>>>(t1, sW2, sb2, sW3, sb3, scores);
}